// Round 1
// baseline (178.616 us; speedup 1.0000x reference)
//
#include <hip/hip_runtime.h>

#define TT 2048
#define DD 384

typedef float f32x4 __attribute__((ext_vector_type(4)));
typedef short s16x8 __attribute__((ext_vector_type(8)));

static __device__ __forceinline__ unsigned short f2bf(float f) {
    unsigned int u = __builtin_bit_cast(unsigned int, f);
    u = (u + 0x7fffu + ((u >> 16) & 1u)) >> 16;
    return (unsigned short)u;
}

// ---------------- fused QKV projection GEMM ----------------
// grid (256 m-blocks, 8 n-blocks) x 256 threads. 64x64 tile, K=384 in 12 steps of 32.
// n-block 0 -> q, 1 -> k (natural [t][64] bf16); 2..7 -> v cols (nb-2)*64, written TRANSPOSED vT[e][t].
__global__ __launch_bounds__(256, 4) void qkv_gemm(
    const float* __restrict__ x, const float* __restrict__ Wq,
    const float* __restrict__ Wk, const float* __restrict__ Wv,
    unsigned short* __restrict__ qo, unsigned short* __restrict__ ko,
    unsigned short* __restrict__ vto)
{
    __shared__ __align__(16) unsigned short lds[4096]; // At[0..2047] Bt[2048..4095]; Ct aliases all
    const int tid = threadIdx.x;
    const int l   = tid & 63;
    const int w   = tid >> 6;
    const int si  = l & 15;
    const int qq  = l >> 4;
    const int m0  = blockIdx.x * 64;
    const int nb  = blockIdx.y;

    const float* W; int ldw, cb;
    if (nb == 0)      { W = Wq; ldw = 64;  cb = 0; }
    else if (nb == 1) { W = Wk; ldw = 64;  cb = 0; }
    else              { W = Wv; ldw = 384; cb = (nb - 2) * 64; }

    f32x4 acc[4];
    #pragma unroll
    for (int nt = 0; nt < 4; ++nt) acc[nt] = (f32x4){0.f, 0.f, 0.f, 0.f};

    const int arow = tid >> 2, ac4 = tid & 3;   // A staging: 64 rows x 4 chunks of 8
    const int brow = tid & 63, bkc = tid >> 6;  // B staging: Bt[n][kd] transpose

    for (int kt = 0; kt < 12; ++kt) {
        const int k0 = kt * 32;
        // stage A: x fp32 -> bf16, swizzled chunks of 8
        const float* xp = x + (size_t)(m0 + arow) * DD + (k0 + ac4 * 8);
        f32x4 x0 = *(const f32x4*)xp;
        f32x4 x1 = *(const f32x4*)(xp + 4);
        s16x8 av;
        av[0] = (short)f2bf(x0[0]); av[1] = (short)f2bf(x0[1]);
        av[2] = (short)f2bf(x0[2]); av[3] = (short)f2bf(x0[3]);
        av[4] = (short)f2bf(x1[0]); av[5] = (short)f2bf(x1[1]);
        av[6] = (short)f2bf(x1[2]); av[7] = (short)f2bf(x1[3]);
        *(s16x8*)&lds[arow * 32 + ((ac4 ^ (arow & 3)) * 8)] = av;
        // stage B transposed: W[kd][n] -> Bt[n][kd] (coalesced across lanes in n)
        const float* wp = W + (size_t)(k0 + bkc * 8) * ldw + (cb + brow);
        s16x8 bv;
        #pragma unroll
        for (int i = 0; i < 8; ++i) bv[i] = (short)f2bf(wp[(size_t)i * ldw]);
        *(s16x8*)&lds[2048 + brow * 32 + ((bkc ^ (brow & 3)) * 8)] = bv;
        __syncthreads();

        const int ar = w * 16 + si;
        s16x8 af = *(const s16x8*)&lds[ar * 32 + ((qq ^ (ar & 3)) * 8)];
        #pragma unroll
        for (int nt = 0; nt < 4; ++nt) {
            const int br = nt * 16 + si;
            s16x8 bf = *(const s16x8*)&lds[2048 + br * 32 + ((qq ^ (br & 3)) * 8)];
            acc[nt] = __builtin_amdgcn_mfma_f32_16x16x32_bf16(af, bf, acc[nt], 0, 0, 0);
        }
        __syncthreads();
    }

    if (nb < 2) {
        unsigned short* dst = (nb == 0) ? qo : ko;
        #pragma unroll
        for (int nt = 0; nt < 4; ++nt)
            #pragma unroll
            for (int r = 0; r < 4; ++r) {
                const int m = w * 16 + qq * 4 + r;
                dst[(size_t)(m0 + m) * 64 + (nt * 16 + si)] = f2bf(acc[nt][r]);
            }
    } else {
        // transpose via LDS: write Ct[n][m] (swizzled), read rows, store vT[e][t] coalesced
        #pragma unroll
        for (int nt = 0; nt < 4; ++nt)
            #pragma unroll
            for (int r = 0; r < 4; ++r) {
                const int m = w * 16 + qq * 4 + r;
                const int n = nt * 16 + si;
                lds[n * 64 + (((m >> 3) ^ (n & 7)) * 8) + (m & 7)] = f2bf(acc[nt][r]);
            }
        __syncthreads();
        const int bb = m0 / TT, t0 = m0 % TT;
        #pragma unroll
        for (int j = 0; j < 2; ++j) {
            const int u = tid + 256 * j;
            const int n = u >> 3, mc = u & 7;
            s16x8 v = *(const s16x8*)&lds[n * 64 + ((mc ^ (n & 7)) * 8)];
            *(s16x8*)&vto[((size_t)bb * DD + (cb + n)) * TT + t0 + mc * 8] = v;
        }
    }
}

// ---------------- flash attention, causal ----------------
// grid 256 x 256 threads. wg -> (batch = wg&7 [XCD-aligned], q-block = wg>>3, 64 rows).
// Wave w: QK^T + online softmax for rows w*16..w*16+15; PV for e-quarter w*96..w*96+95 of ALL 64 rows.
__global__ __launch_bounds__(256, 2) void attn(
    const unsigned short* __restrict__ qg, const unsigned short* __restrict__ kg,
    const unsigned short* __restrict__ vg, float* __restrict__ out,
    float* __restrict__ gstats)
{
    __shared__ __align__(16) unsigned short lds[32768]; // Kt 8KB | Vt 48KB | P 8KB  (= 64KB)
    unsigned short* KtL = lds;
    unsigned short* VtL = lds + 4096;
    unsigned short* PL  = lds + 28672;

    const int tid = threadIdx.x;
    const int l   = tid & 63;
    const int w   = tid >> 6;
    const int si  = l & 15;
    const int qq  = l >> 4;
    const int wg  = blockIdx.x;
    const int bb  = wg & 7;
    const int qblk = wg >> 3;
    const int q0  = qblk * 64;

    float* st = gstats + (size_t)wg * 64;

    // q fragments straight from global (rows w*16+si, kk chunks)
    s16x8 qf[2];
    {
        const unsigned short* qp = qg + ((size_t)bb * TT + q0 + w * 16 + si) * 64 + qq * 8;
        qf[0] = *(const s16x8*)qp;
        qf[1] = *(const s16x8*)(qp + 32);
    }

    f32x4 o[4][6];
    #pragma unroll
    for (int rt = 0; rt < 4; ++rt)
        #pragma unroll
        for (int et = 0; et < 6; ++et) o[rt][et] = (f32x4){0.f, 0.f, 0.f, 0.f};
    float m_i[4] = {-1e30f, -1e30f, -1e30f, -1e30f};
    float l_i[4] = {0.f, 0.f, 0.f, 0.f};

    for (int blk = 0; blk <= qblk; ++blk) {
        const int s0 = blk * 64;
        // stage K tile [si][kk] (swizzled)
        #pragma unroll
        for (int i = 0; i < 2; ++i) {
            const int u = tid + 256 * i;
            const int row = u >> 3, kc = u & 7;
            s16x8 v = *(const s16x8*)(kg + ((size_t)bb * TT + s0 + row) * 64 + kc * 8);
            *(s16x8*)&KtL[row * 64 + ((kc ^ (row & 7)) * 8)] = v;
        }
        // stage V^T tile [e][s] (swizzled)
        #pragma unroll
        for (int i = 0; i < 12; ++i) {
            const int u = tid + 256 * i;
            const int e = u >> 3, sc = u & 7;
            s16x8 v = *(const s16x8*)(vg + ((size_t)bb * DD + e) * TT + s0 + sc * 8);
            *(s16x8*)&VtL[e * 64 + ((sc ^ (e & 7)) * 8)] = v;
        }
        __syncthreads();

        // S = q @ k^T for own 16 rows
        f32x4 S[4];
        #pragma unroll
        for (int nt = 0; nt < 4; ++nt) S[nt] = (f32x4){0.f, 0.f, 0.f, 0.f};
        #pragma unroll
        for (int c = 0; c < 2; ++c)
            #pragma unroll
            for (int nt = 0; nt < 4; ++nt) {
                const int row = nt * 16 + si;
                s16x8 bf = *(const s16x8*)&KtL[row * 64 + (((c * 4 + qq) ^ (row & 7)) * 8)];
                S[nt] = __builtin_amdgcn_mfma_f32_16x16x32_bf16(qf[c], bf, S[nt], 0, 0, 0);
            }
        #pragma unroll
        for (int nt = 0; nt < 4; ++nt)
            #pragma unroll
            for (int r = 0; r < 4; ++r) S[nt][r] *= 0.125f;
        if (blk == qblk) { // diagonal block: mask local col > local row
            #pragma unroll
            for (int nt = 0; nt < 4; ++nt) {
                const int col = nt * 16 + si;
                #pragma unroll
                for (int r = 0; r < 4; ++r)
                    if (col > w * 16 + qq * 4 + r) S[nt][r] = -1e30f;
            }
        }
        // online softmax over 64 cols (4 tiles in-lane + 16-lane butterfly)
        float mx[4], al[4];
        #pragma unroll
        for (int r = 0; r < 4; ++r)
            mx[r] = fmaxf(fmaxf(S[0][r], S[1][r]), fmaxf(S[2][r], S[3][r]));
        #pragma unroll
        for (int off = 1; off < 16; off <<= 1)
            #pragma unroll
            for (int r = 0; r < 4; ++r) mx[r] = fmaxf(mx[r], __shfl_xor(mx[r], off));
        #pragma unroll
        for (int r = 0; r < 4; ++r) {
            const float mn = fmaxf(m_i[r], mx[r]);
            al[r] = __expf(m_i[r] - mn);
            m_i[r] = mn;
        }
        #pragma unroll
        for (int nt = 0; nt < 4; ++nt)
            #pragma unroll
            for (int r = 0; r < 4; ++r) S[nt][r] = __expf(S[nt][r] - m_i[r]);
        float rs[4];
        #pragma unroll
        for (int r = 0; r < 4; ++r) rs[r] = (S[0][r] + S[1][r]) + (S[2][r] + S[3][r]);
        #pragma unroll
        for (int off = 1; off < 16; off <<= 1)
            #pragma unroll
            for (int r = 0; r < 4; ++r) rs[r] += __shfl_xor(rs[r], off);
        #pragma unroll
        for (int r = 0; r < 4; ++r) l_i[r] = l_i[r] * al[r] + rs[r];

        // write P (bf16, A-operand layout rows w*16..) + share alpha via ws
        #pragma unroll
        for (int nt = 0; nt < 4; ++nt)
            #pragma unroll
            for (int r = 0; r < 4; ++r) {
                const int m = w * 16 + qq * 4 + r;
                const int col = nt * 16 + si;
                PL[m * 64 + (((col >> 3) ^ (m & 7)) * 8) + (col & 7)] = f2bf(S[nt][r]);
            }
        if (si == 0) {
            f32x4 av = {al[0], al[1], al[2], al[3]};
            *(f32x4*)&st[w * 16 + qq * 4] = av;
        }
        __syncthreads();

        // rescale O by alpha (rows match f32x4 components), then O += P @ V
        #pragma unroll
        for (int rt = 0; rt < 4; ++rt) {
            f32x4 af = *(const f32x4*)&st[rt * 16 + qq * 4];
            #pragma unroll
            for (int et = 0; et < 6; ++et) o[rt][et] = o[rt][et] * af;
        }
        #pragma unroll
        for (int c = 0; c < 2; ++c) {
            s16x8 a[4];
            #pragma unroll
            for (int rt = 0; rt < 4; ++rt) {
                const int row = rt * 16 + si;
                a[rt] = *(const s16x8*)&PL[row * 64 + (((c * 4 + qq) ^ (row & 7)) * 8)];
            }
            #pragma unroll
            for (int et = 0; et < 6; ++et) {
                const int e = w * 96 + et * 16 + si;
                s16x8 bf = *(const s16x8*)&VtL[e * 64 + (((c * 4 + qq) ^ (e & 7)) * 8)];
                #pragma unroll
                for (int rt = 0; rt < 4; ++rt)
                    o[rt][et] = __builtin_amdgcn_mfma_f32_16x16x32_bf16(a[rt], bf, o[rt][et], 0, 0, 0);
            }
        }
        __syncthreads();
    }

    // share l, normalize, write fp32 out
    if (si == 0) {
        f32x4 lv = {l_i[0], l_i[1], l_i[2], l_i[3]};
        *(f32x4*)&st[w * 16 + qq * 4] = lv;
    }
    __syncthreads();
    #pragma unroll
    for (int rt = 0; rt < 4; ++rt) {
        f32x4 lf = *(const f32x4*)&st[rt * 16 + qq * 4];
        f32x4 inv;
        #pragma unroll
        for (int r = 0; r < 4; ++r) inv[r] = 1.f / lf[r];
        #pragma unroll
        for (int et = 0; et < 6; ++et) {
            f32x4 v = o[rt][et] * inv;
            #pragma unroll
            for (int r = 0; r < 4; ++r)
                out[((size_t)bb * TT + (q0 + rt * 16 + qq * 4 + r)) * DD + (w * 96 + et * 16 + si)] = v[r];
        }
    }
}

extern "C" void kernel_launch(void* const* d_in, const int* in_sizes, int n_in,
                              void* d_out, int out_size, void* d_ws, size_t ws_size,
                              hipStream_t stream)
{
    const float* x  = (const float*)d_in[0];
    const float* Wq = (const float*)d_in[1];
    const float* Wk = (const float*)d_in[2];
    const float* Wv = (const float*)d_in[3];

    // ws layout (bytes): q[0,2M) k[2M,4M) vT[4M,16M) stats[16M,16M+64K)
    unsigned short* qws  = (unsigned short*)d_ws;
    unsigned short* kws  = (unsigned short*)((char*)d_ws + ((size_t)2 << 20));
    unsigned short* vtws = (unsigned short*)((char*)d_ws + ((size_t)4 << 20));
    float* stats         = (float*)((char*)d_ws + ((size_t)16 << 20));

    qkv_gemm<<<dim3(256, 8), dim3(256), 0, stream>>>(x, Wq, Wk, Wv, qws, kws, vtws);
    attn<<<dim3(256), dim3(256), 0, stream>>>(qws, kws, vtws, (float*)d_out, stats);
}